// Round 8
// baseline (320.687 us; speedup 1.0000x reference)
//
#include <hip/hip_runtime.h>
#include <hip/hip_bf16.h>

typedef __attribute__((ext_vector_type(8))) short short8;
typedef __attribute__((ext_vector_type(4))) float float4v;
typedef __attribute__((ext_vector_type(2))) unsigned int uint2v;

#define MFMA_BF16 __builtin_amdgcn_mfma_f32_16x16x32_bf16

__device__ __forceinline__ unsigned short f2b(float f) {
  union { float f; unsigned u; } v; v.f = f;
  unsigned r = v.u + 0x7FFFu + ((v.u >> 16) & 1u);  // round-to-nearest-even
  return (unsigned short)(r >> 16);
}

__device__ __forceinline__ unsigned pk2(float x, float y) {
  float2 v; v.x = x; v.y = y;
  __hip_bfloat162 h = __float22bfloat162_rn(v);
  union { __hip_bfloat162 h; unsigned u; } c; c.h = h;
  return c.u;
}

// async global->LDS, 16B per lane. LDS dest must be wave-uniform + lane*16.
__device__ __forceinline__ void gld16(const unsigned short* g, unsigned short* l) {
  __builtin_amdgcn_global_load_lds(
      (const __attribute__((address_space(1))) unsigned int*)g,
      (__attribute__((address_space(3))) unsigned int*)l, 16, 0, 0);
}

// Swizzled element index within a [rows][64] bf16 LDS tile.
__device__ __forceinline__ int swa(int r, int k) {
  return (r << 6) + ((((k >> 3) ^ r ^ (r >> 3)) & 7) << 3) + (k & 7);
}

// QKV GEMM v5 (RESUBMIT — r7 bench died at container acquire, not kernel):
// cast FUSED into staging. Inputs are the raw f32 hs and Wq/Wk/Wv; staging
// is reg-staged (global f32x4 -> v_cvt_pk_bf16 -> swizzled ds_write_b128,
// rule-21 both-sides swizzle: linear source, swizzled write, swizzled read).
// Removes the cast_all kernel (launch + 12 us) and the Xb/Wb bf16 workspace
// round-trip (~75 MB HBM), at the cost of 12 loads + 24 cvt + 6 ds_writes
// per thread per tile issued T14-style (load-early before COMPUTE,
// cvt+write-late after). BM=256 BN=128 BK=64, 8 waves (4M x 2N), dbuf 96 KB
// dynamic LDS, one barrier per tile. Grid 1152, XCD-swizzled.
// z=0 out pre-scaled by log2(e)/sqrt(64); z=2 transposed to [b][h][d][s].
__global__ __launch_bounds__(512) void qkv_gemm(
    const float* __restrict__ Xf, const float* __restrict__ Wqf,
    const float* __restrict__ Wkf, const float* __restrict__ Wvf,
    const float* __restrict__ b0, const float* __restrict__ b1, const float* __restrict__ b2,
    unsigned short* __restrict__ O0, unsigned short* __restrict__ O1, unsigned short* __restrict__ OVT) {
  extern __shared__ __align__(16) unsigned short LDS[];  // 2 * (16384 A + 8192 B)

  // XCD swizzle: xcd g&7 owns origs [xcd*144,+144) = 8 m-blocks x 18 n-blocks.
  const int g = blockIdx.x;
  const int orig = (g & 7) * 144 + (g >> 3);
  const int mblk = orig / 18;
  const int nblk = orig - mblk * 18;
  const int m0 = mblk * 256, n0p = nblk * 128;
  const int zz = n0p / 768;          // uniform per block
  const int nbase = n0p - zz * 768;  // local n within z
  const float* Wf = (zz == 0) ? Wqf : (zz == 1 ? Wkf : Wvf);

  const int t = threadIdx.x, w = t >> 6, l = t & 63, qd = l >> 4, col = l & 15;
  const int wm64 = (w & 3) * 64, wn64 = (w >> 2) * 64;
  const int qd8 = qd * 8;

  // Chunk geometry: 16B bf16 chunk (r, j): elements k = j*8..j*8+7 of row r.
  // j = t&7 for every chunk; A rows: i*64 + (t>>3), i<4; B rows: i*64+(t>>3), i<2.
  const int j = t & 7, tr = t >> 3;
  const int rA0 = tr, rA1 = 64 + tr, rA2 = 128 + tr, rA3 = 192 + tr;
  const int rB0 = tr, rB1 = 64 + tr;
  // Swizzled LDS element offsets (write side; read side uses swa()).
  const int dA0 = (rA0 << 6) + (((j ^ rA0 ^ (rA0 >> 3)) & 7) << 3);
  const int dA1 = (rA1 << 6) + (((j ^ rA1 ^ (rA1 >> 3)) & 7) << 3);
  const int dA2 = (rA2 << 6) + (((j ^ rA2 ^ (rA2 >> 3)) & 7) << 3);
  const int dA3 = (rA3 << 6) + (((j ^ rA3 ^ (rA3 >> 3)) & 7) << 3);
  const int dB0 = (rB0 << 6) + (((j ^ rB0 ^ (rB0 >> 3)) & 7) << 3);
  const int dB1 = (rB1 << 6) + (((j ^ rB1 ^ (rB1 >> 3)) & 7) << 3);
  // Linear f32 sources.
  const float* XA0 = Xf + (size_t)(m0 + rA0) * 768 + j * 8;
  const float* XA1 = Xf + (size_t)(m0 + rA1) * 768 + j * 8;
  const float* XA2 = Xf + (size_t)(m0 + rA2) * 768 + j * 8;
  const float* XA3 = Xf + (size_t)(m0 + rA3) * 768 + j * 8;
  const float* WB0 = Wf + (size_t)(nbase + rB0) * 768 + j * 8;
  const float* WB1 = Wf + (size_t)(nbase + rB1) * 768 + j * 8;

  float4 a0, a1, a2, a3, a4, a5, a6, a7, g0, g1, g2, g3;

#define LOADR(kt)                                              \
  do {                                                         \
    const int kk_ = (kt)*64;                                   \
    a0 = *(const float4*)(XA0 + kk_); a1 = *(const float4*)(XA0 + kk_ + 4); \
    a2 = *(const float4*)(XA1 + kk_); a3 = *(const float4*)(XA1 + kk_ + 4); \
    a4 = *(const float4*)(XA2 + kk_); a5 = *(const float4*)(XA2 + kk_ + 4); \
    a6 = *(const float4*)(XA3 + kk_); a7 = *(const float4*)(XA3 + kk_ + 4); \
    g0 = *(const float4*)(WB0 + kk_); g1 = *(const float4*)(WB0 + kk_ + 4); \
    g2 = *(const float4*)(WB1 + kk_); g3 = *(const float4*)(WB1 + kk_ + 4); \
  } while (0)

#define CVW(base, dst, lo, hi)                                 \
  do {                                                         \
    uint4 pv_;                                                 \
    pv_.x = pk2(lo.x, lo.y); pv_.y = pk2(lo.z, lo.w);          \
    pv_.z = pk2(hi.x, hi.y); pv_.w = pk2(hi.z, hi.w);          \
    *(uint4*)&base[dst] = pv_;                                 \
  } while (0)

#define WRITEALL(sb)                                           \
  do {                                                         \
    unsigned short* SA_ = LDS + (sb)*24576;                    \
    unsigned short* SB_ = SA_ + 16384;                         \
    CVW(SA_, dA0, a0, a1);                                     \
    CVW(SA_, dA1, a2, a3);                                     \
    CVW(SA_, dA2, a4, a5);                                     \
    CVW(SA_, dA3, a6, a7);                                     \
    CVW(SB_, dB0, g0, g1);                                     \
    CVW(SB_, dB1, g2, g3);                                     \
  } while (0)

  float4v acc[4][4];
#pragma unroll
  for (int i = 0; i < 4; ++i)
#pragma unroll
    for (int jj = 0; jj < 4; ++jj) acc[i][jj] = (float4v)0.0f;

#define COMPUTE(cur)                                                          \
  do {                                                                        \
    const unsigned short* Ar_ = LDS + (cur)*24576;                            \
    const unsigned short* Br_ = Ar_ + 16384;                                  \
    _Pragma("unroll") for (int ks = 0; ks < 2; ++ks) {                        \
      short8 af[4], bf[4];                                                    \
      _Pragma("unroll") for (int mi = 0; mi < 4; ++mi)                        \
          af[mi] = *(const short8*)&Ar_[swa(wm64 + mi * 16 + col,             \
                                            ks * 32 + qd8)];                  \
      _Pragma("unroll") for (int ni = 0; ni < 4; ++ni)                        \
          bf[ni] = *(const short8*)&Br_[swa(wn64 + ni * 16 + col,             \
                                            ks * 32 + qd8)];                  \
      __builtin_amdgcn_s_setprio(1);                                          \
      _Pragma("unroll") for (int mi = 0; mi < 4; ++mi)                        \
          _Pragma("unroll") for (int ni = 0; ni < 4; ++ni)                    \
          acc[mi][ni] = MFMA_BF16(af[mi], bf[ni], acc[mi][ni], 0, 0, 0);      \
      __builtin_amdgcn_s_setprio(0);                                          \
    }                                                                         \
  } while (0)

  // Prologue: tile 0 -> buf 0.
  LOADR(0);
  WRITEALL(0);
  __syncthreads();

  int cur = 0;
#pragma unroll 1
  for (int kt = 0; kt < 11; ++kt) {
    LOADR(kt + 1);                        // issue loads early
    __builtin_amdgcn_sched_barrier(0);    // pin them before COMPUTE
    COMPUTE(cur);                         // MFMA phase hides load latency
    WRITEALL(cur ^ 1);                    // cvt+write (data-dep waits vmcnt)
    __syncthreads();
    cur ^= 1;
  }
  COMPUTE(cur);  // tile 11

  if (zz < 2) {
    unsigned short* O = (zz == 0) ? O0 : O1;
    const float* bias = (zz == 0) ? b0 : b1;
    const float osc = (zz == 0) ? 0.18033688f : 1.0f;  // log2(e)/sqrt(64) into Q
#pragma unroll
    for (int ni = 0; ni < 4; ++ni) {
      const int n = nbase + wn64 + ni * 16 + col;
      const float bb = bias[n];
#pragma unroll
      for (int mi = 0; mi < 4; ++mi)
#pragma unroll
        for (int r = 0; r < 4; ++r) {
          const int m = m0 + wm64 + mi * 16 + qd * 4 + r;
          O[(size_t)m * 768 + n] = f2b((acc[mi][ni][r] + bb) * osc);
        }
    }
  } else {
    // V^T via LDS transpose: T[nl][ml] 128x256 ushort (64 KB), chunk
    // XOR-swizzled.
    __syncthreads();  // all waves done with k-loop LDS
    unsigned short* T = LDS;
#pragma unroll
    for (int ni = 0; ni < 4; ++ni) {
      const int nl = wn64 + ni * 16 + col;
      const float bb = b2[nbase + nl];
#pragma unroll
      for (int mi = 0; mi < 4; ++mi) {
        const int ml = wm64 + mi * 16 + qd * 4;
        const int mc = ml >> 3;
        ushort4 o;
        o.x = f2b(acc[mi][ni][0] + bb);
        o.y = f2b(acc[mi][ni][1] + bb);
        o.z = f2b(acc[mi][ni][2] + bb);
        o.w = f2b(acc[mi][ni][3] + bb);
        *(ushort4*)&T[(nl << 8) + (((mc ^ (nl & 31)) & 31) << 3) + (ml & 7)] = o;
      }
    }
    __syncthreads();
    const int nl2 = t >> 2;        // 0..127
    const int seg = t & 3;         // 0..3 (64 m each)
    const int nglob = nbase + nl2; // 0..767
    const int hh = nglob >> 6, dd = nglob & 63;
    const int bb2 = m0 >> 10;
    unsigned short* dstp =
        &OVT[(((size_t)bb2 * 12 + hh) * 64 + dd) * 1024 + (m0 & 1023) + seg * 64];
#pragma unroll
    for (int jj = 0; jj < 8; ++jj) {
      const int mc = seg * 8 + jj;
      uint4 vv = *(const uint4*)&T[(nl2 << 8) + (((mc ^ (nl2 & 31)) & 31) << 3)];
      *(uint4*)&dstp[jj * 8] = vv;
    }
  }
#undef LOADR
#undef CVW
#undef WRITEALL
#undef COMPUTE
}

// Flash attention v7 (r5 config — best measured): V staged in LDS (dbuf),
// setprio around QK and PV MFMA clusters, in-register P transform
// (cvt_pk + permlane32/16_swap), ones-MFMA row-sum, Q pre-scaled,
// XCD-clustered flat grid. LDS 32 KB, 256 threads.
__global__ __launch_bounds__(256) void attn(
    const unsigned short* __restrict__ Q, const unsigned short* __restrict__ K,
    const unsigned short* __restrict__ VT, float* __restrict__ O) {
  __shared__ __align__(16) unsigned short Ks0[4096];
  __shared__ __align__(16) unsigned short Ks1[4096];
  __shared__ __align__(16) unsigned short Vt0[4096];
  __shared__ __align__(16) unsigned short Vt1[4096];

  const int g = blockIdx.x;
  const int orig = (g & 7) * 192 + (g >> 3);
  const int qt = orig & 7;
  const int hb = orig >> 3;  // h + 12*b
  const int b = hb / 12;
  const int h = hb - b * 12;

  const int t = threadIdx.x, w = t >> 6, l = t & 63, qd = l >> 4, col = l & 15;
  const size_t bh = (size_t)b * 786432 + (size_t)h * 64;
  const unsigned short* Kb = K + bh;
  const unsigned short* VTb = VT + ((size_t)(b * 12 + h)) * 65536;

  short8 qf[2][2];
  {
    const unsigned short* Qg = Q + bh + (size_t)(qt * 128 + w * 32) * 768;
#pragma unroll
    for (int mi = 0; mi < 2; ++mi)
#pragma unroll
      for (int ks = 0; ks < 2; ++ks)
        qf[mi][ks] =
            *(const short8*)&Qg[(size_t)(mi * 16 + col) * 768 + ks * 32 + qd * 8];
  }

  const int c0 = t, c1 = 256 + t;
  const int r0 = c0 >> 3, cc0 = (c0 ^ r0 ^ (r0 >> 3)) & 7;
  const int r1 = c1 >> 3, cc1 = (c1 ^ r1 ^ (r1 >> 3)) & 7;

#define STAGE_K(ktile, dst)                                             \
  do {                                                                  \
    const unsigned short* Kg_ = Kb + (size_t)(ktile)*49152;             \
    gld16(&Kg_[(size_t)r0 * 768 + cc0 * 8], &dst[c0 * 8]);              \
    gld16(&Kg_[(size_t)r1 * 768 + cc1 * 8], &dst[c1 * 8]);              \
  } while (0)

#define STAGE_V(ktile, dst)                                             \
  do {                                                                  \
    const unsigned short* Vg_ = VTb + (ktile)*64;                       \
    gld16(&Vg_[(size_t)r0 * 1024 + cc0 * 8], &dst[c0 * 8]);             \
    gld16(&Vg_[(size_t)r1 * 1024 + cc1 * 8], &dst[c1 * 8]);             \
  } while (0)

  STAGE_K(0, Ks0);
  STAGE_V(0, Vt0);

  float4v acc[2][4];
  float4v accl[2];
#pragma unroll
  for (int mi = 0; mi < 2; ++mi) {
    accl[mi] = (float4v)0.0f;
#pragma unroll
    for (int dt = 0; dt < 4; ++dt) acc[mi][dt] = (float4v)0.0f;
  }

  short8 ones;
#pragma unroll
  for (int jj = 0; jj < 8; ++jj) ones[jj] = (short)0x3F80;  // bf16 1.0

  __syncthreads();

#define ATTN_ITER(kt, KsR, VtR, KsW, VtW)                                 \
  do {                                                                    \
    if ((kt) < 15) {                                                      \
      STAGE_K((kt) + 1, KsW);                                             \
      STAGE_V((kt) + 1, VtW);                                             \
    }                                                                     \
    short8 kf[2][4];                                                      \
    _Pragma("unroll") for (int ks = 0; ks < 2; ++ks)                      \
        _Pragma("unroll") for (int ni = 0; ni < 4; ++ni)                  \
        kf[ks][ni] =                                                      \
        *(const short8*)&KsR[swa(ni * 16 + col, ks * 32 + qd * 8)];       \
    float4v sT[2][4];                                                     \
    _Pragma("unroll") for (int mi = 0; mi < 2; ++mi)                      \
        _Pragma("unroll") for (int ni = 0; ni < 4; ++ni)                  \
        sT[mi][ni] = (float4v)0.0f;                                       \
    __builtin_amdgcn_s_setprio(1);                                        \
    _Pragma("unroll") for (int ks = 0; ks < 2; ++ks)                      \
        _Pragma("unroll") for (int ni = 0; ni < 4; ++ni) {                \
      sT[0][ni] = MFMA_BF16(kf[ks][ni], qf[0][ks], sT[0][ni], 0, 0, 0);   \
      sT[1][ni] = MFMA_BF16(kf[ks][ni], qf[1][ks], sT[1][ni], 0, 0, 0);   \
    }                                                                     \
    __builtin_amdgcn_s_setprio(0);                                        \
    _Pragma("unroll") for (int s = 0; s < 2; ++s) {                       \
      short8 pf[2];                                                       \
      _Pragma("unroll") for (int mi = 0; mi < 2; ++mi) {                  \
        float4v sa = sT[mi][s * 2 + 0];                                   \
        float4v sb = sT[mi][s * 2 + 1];                                   \
        unsigned A0 = pk2(__builtin_amdgcn_exp2f(sa[0]),                  \
                          __builtin_amdgcn_exp2f(sa[1]));                 \
        unsigned A1 = pk2(__builtin_amdgcn_exp2f(sa[2]),                  \
                          __builtin_amdgcn_exp2f(sa[3]));                 \
        unsigned B0 = pk2(__builtin_amdgcn_exp2f(sb[0]),                  \
                          __builtin_amdgcn_exp2f(sb[1]));                 \
        unsigned B1 = pk2(__builtin_amdgcn_exp2f(sb[2]),                  \
                          __builtin_amdgcn_exp2f(sb[3]));                 \
        uint2v x0 = __builtin_amdgcn_permlane32_swap(A0, B0, false, false);   \
        uint2v x1 = __builtin_amdgcn_permlane32_swap(A1, B1, false, false);   \
        uint2v y02 = __builtin_amdgcn_permlane16_swap(x0[0], x0[1], false, false); \
        uint2v y13 = __builtin_amdgcn_permlane16_swap(x1[0], x1[1], false, false); \
        union { unsigned u[4]; short8 v; } pu;                            \
        pu.u[0] = y02[0]; pu.u[1] = y13[0];                               \
        pu.u[2] = y02[1]; pu.u[3] = y13[1];                               \
        pf[mi] = pu.v;                                                    \
      }                                                                   \
      const int kk = s * 32 + qd * 8;                                     \
      __builtin_amdgcn_s_setprio(1);                                      \
      _Pragma("unroll") for (int dt = 0; dt < 4; ++dt) {                  \
        short8 vf = *(const short8*)&VtR[swa(dt * 16 + col, kk)];         \
        acc[0][dt] = MFMA_BF16(vf, pf[0], acc[0][dt], 0, 0, 0);           \
        acc[1][dt] = MFMA_BF16(vf, pf[1], acc[1][dt], 0, 0, 0);           \
      }                                                                   \
      accl[0] = MFMA_BF16(ones, pf[0], accl[0], 0, 0, 0);                 \
      accl[1] = MFMA_BF16(ones, pf[1], accl[1], 0, 0, 0);                 \
      __builtin_amdgcn_s_setprio(0);                                      \
    }                                                                     \
    __syncthreads();                                                      \
  } while (0)

  for (int kt2 = 0; kt2 < 16; kt2 += 2) {
    ATTN_ITER(kt2, Ks0, Vt0, Ks1, Vt1);
    ATTN_ITER(kt2 + 1, Ks1, Vt1, Ks0, Vt0);
  }

  float* Og = O + (size_t)(b * 1024 + qt * 128) * 768 + h * 64;
#pragma unroll
  for (int mi = 0; mi < 2; ++mi) {
    const float rl = 1.0f / accl[mi][0];
    const int q = w * 32 + mi * 16 + col;
#pragma unroll
    for (int dt = 0; dt < 4; ++dt) {
      float4 o;
      o.x = acc[mi][dt][0] * rl;
      o.y = acc[mi][dt][1] * rl;
      o.z = acc[mi][dt][2] * rl;
      o.w = acc[mi][dt][3] * rl;
      *(float4*)&Og[(size_t)q * 768 + dt * 16 + qd * 4] = o;
    }
  }
#undef STAGE_K
#undef STAGE_V
#undef ATTN_ITER
}

extern "C" void kernel_launch(void* const* d_in, const int* in_sizes, int n_in,
                              void* d_out, int out_size, void* d_ws, size_t ws_size,
                              hipStream_t stream) {
  const float* hs = (const float*)d_in[0];
  const float* Wq = (const float*)d_in[1];
  const float* bq = (const float*)d_in[2];
  const float* Wk = (const float*)d_in[3];
  const float* bk = (const float*)d_in[4];
  const float* Wv = (const float*)d_in[5];
  const float* bv = (const float*)d_in[6];
  float* out = (float*)d_out;
  char* ws = (char*)d_ws;

  unsigned short* Qb = (unsigned short*)ws;
  unsigned short* Kb = (unsigned short*)(ws + 25165824);
  unsigned short* Vb = (unsigned short*)(ws + 50331648);  // V^T [b][h][d][s]

  static bool attr_set = false;
  if (!attr_set) {
    hipFuncSetAttribute((const void*)qkv_gemm,
                        hipFuncAttributeMaxDynamicSharedMemorySize, 98304);
    attr_set = true;
  }

  qkv_gemm<<<dim3(1152), 512, 98304, stream>>>(hs, Wq, Wk, Wv, bq, bk, bv,
                                               Qb, Kb, Vb);

  attn<<<dim3(1536), 256, 0, stream>>>(Qb, Kb, Vb, out);
}

// Round 9
// 260.042 us; speedup vs baseline: 1.2332x; 1.2332x over previous
//
#include <hip/hip_runtime.h>
#include <hip/hip_bf16.h>

typedef __attribute__((ext_vector_type(8))) short short8;
typedef __attribute__((ext_vector_type(4))) float float4v;
typedef __attribute__((ext_vector_type(2))) unsigned int uint2v;

#define MFMA_BF16 __builtin_amdgcn_mfma_f32_16x16x32_bf16

__device__ __forceinline__ unsigned short f2b(float f) {
  union { float f; unsigned u; } v; v.f = f;
  unsigned r = v.u + 0x7FFFu + ((v.u >> 16) & 1u);  // round-to-nearest-even
  return (unsigned short)(r >> 16);
}

__device__ __forceinline__ unsigned pk2(float x, float y) {
  float2 v; v.x = x; v.y = y;
  __hip_bfloat162 h = __float22bfloat162_rn(v);
  union { __hip_bfloat162 h; unsigned u; } c; c.h = h;
  return c.u;
}

// async global->LDS, 16B per lane. LDS dest must be wave-uniform + lane*16.
__device__ __forceinline__ void gld16(const unsigned short* g, unsigned short* l) {
  __builtin_amdgcn_global_load_lds(
      (const __attribute__((address_space(1))) unsigned int*)g,
      (__attribute__((address_space(3))) unsigned int*)l, 16, 0, 0);
}

// Swizzled element index within a [rows][64] bf16 LDS tile.
__device__ __forceinline__ int swa(int r, int k) {
  return (r << 6) + ((((k >> 3) ^ r ^ (r >> 3)) & 7) << 3) + (k & 7);
}

// Fused cast: hs (12288 blocks) + Wq/Wk/Wv (576 blocks each) in one launch.
// (r8 lesson: do NOT fuse this into the GEMM — the GEMM re-reads its operands
// ~3x; casting once keeps those re-reads bf16. Fusion doubled staged bytes
// and cost +80 us.)
__global__ __launch_bounds__(256) void cast_all(
    const float* __restrict__ hs, const float* __restrict__ Wq,
    const float* __restrict__ Wk, const float* __restrict__ Wv,
    unsigned short* __restrict__ Xb, unsigned short* __restrict__ Wb) {
  const int blk = blockIdx.x;
  const float* src;
  unsigned short* dst;
  int i;
  if (blk < 12288) {
    i = blk * 256 + threadIdx.x;
    src = hs;
    dst = Xb;
  } else {
    const int x = blk - 12288;       // 0..1727
    const int z = x / 576;           // 0,1,2
    i = (x - z * 576) * 256 + threadIdx.x;
    src = (z == 0) ? Wq : (z == 1 ? Wk : Wv);
    dst = Wb + (size_t)z * 589824;
  }
  float4 f = ((const float4*)src)[i];
  uint2 o;
  o.x = pk2(f.x, f.y);
  o.y = pk2(f.z, f.w);
  ((uint2*)dst)[i] = o;
}

// QKV GEMM v2 (verified 87 us): BM=256 BN=128 BK=64, 8 waves (4M x 2N),
// per-wave 64x64 out. TRIPLE-buffered LDS (144 KB dynamic, 1 block/CU),
// prefetch depth 2: STAGE(t+2) at tile-t top, per-tile counted s_waitcnt
// vmcnt(6). Raw s_barrier once per tile. Grid 1152, XCD-swizzled.
// z=0 out pre-scaled by log2(e)/sqrt(64); z=2 transposed to [b][h][d][s].
__global__ __launch_bounds__(512) void qkv_gemm(
    const unsigned short* __restrict__ X, const unsigned short* __restrict__ Wall,
    const float* __restrict__ b0, const float* __restrict__ b1, const float* __restrict__ b2,
    unsigned short* __restrict__ O0, unsigned short* __restrict__ O1, unsigned short* __restrict__ OVT) {
  extern __shared__ __align__(16) unsigned short LDS[];  // 3 * (16384 A + 8192 B)

  // XCD swizzle: xcd g&7 owns origs [xcd*144,+144) = 8 m-blocks x 18 n-blocks.
  const int g = blockIdx.x;
  const int orig = (g & 7) * 144 + (g >> 3);
  const int mblk = orig / 18;
  const int nblk = orig - mblk * 18;
  const int m0 = mblk * 256, n0p = nblk * 128;

  const int t = threadIdx.x, w = t >> 6, l = t & 63, qd = l >> 4, col = l & 15;
  const int wm64 = (w & 3) * 64, wn64 = (w >> 2) * 64;
  const int qd8 = qd * 8;

  // Per-thread staging slots: A tile 2048 chunks (4 loads), B tile 1024 (2).
  const int cA0 = t, cA1 = 512 + t, cA2 = 1024 + t, cA3 = 1536 + t;
  const int rA0 = cA0 >> 3, rA1 = cA1 >> 3, rA2 = cA2 >> 3, rA3 = cA3 >> 3;
  const int pA0 = (cA0 ^ rA0 ^ (rA0 >> 3)) & 7, pA1 = (cA1 ^ rA1 ^ (rA1 >> 3)) & 7;
  const int pA2 = (cA2 ^ rA2 ^ (rA2 >> 3)) & 7, pA3 = (cA3 ^ rA3 ^ (rA3 >> 3)) & 7;
  const int cB0 = t, cB1 = 512 + t;
  const int rB0 = cB0 >> 3, rB1 = cB1 >> 3;
  const int pB0 = (cB0 ^ rB0 ^ (rB0 >> 3)) & 7, pB1 = (cB1 ^ rB1 ^ (rB1 >> 3)) & 7;

  const unsigned short* Xa0 = X + (size_t)(m0 + rA0) * 768 + pA0 * 8;
  const unsigned short* Xa1 = X + (size_t)(m0 + rA1) * 768 + pA1 * 8;
  const unsigned short* Xa2 = X + (size_t)(m0 + rA2) * 768 + pA2 * 8;
  const unsigned short* Xa3 = X + (size_t)(m0 + rA3) * 768 + pA3 * 8;
  const unsigned short* Wb0 = Wall + (size_t)(n0p + rB0) * 768 + pB0 * 8;
  const unsigned short* Wb1 = Wall + (size_t)(n0p + rB1) * 768 + pB1 * 8;
  const int dA0 = cA0 * 8, dA1 = cA1 * 8, dA2 = cA2 * 8, dA3 = cA3 * 8;
  const int dB0 = cB0 * 8, dB1 = cB1 * 8;

#define STAGE(kt, sb)                                         \
  do {                                                        \
    unsigned short* SA_ = LDS + (sb)*24576;                   \
    unsigned short* SB_ = SA_ + 16384;                        \
    const int kk_ = (kt)*64;                                  \
    gld16(Xa0 + kk_, SA_ + dA0);                              \
    gld16(Xa1 + kk_, SA_ + dA1);                              \
    gld16(Xa2 + kk_, SA_ + dA2);                              \
    gld16(Xa3 + kk_, SA_ + dA3);                              \
    gld16(Wb0 + kk_, SB_ + dB0);                              \
    gld16(Wb1 + kk_, SB_ + dB1);                              \
  } while (0)

  float4v acc[4][4];
#pragma unroll
  for (int i = 0; i < 4; ++i)
#pragma unroll
    for (int j = 0; j < 4; ++j) acc[i][j] = (float4v)0.0f;

#define COMPUTE(cur)                                                          \
  do {                                                                        \
    const unsigned short* Ar_ = LDS + (cur)*24576;                            \
    const unsigned short* Br_ = Ar_ + 16384;                                  \
    _Pragma("unroll") for (int ks = 0; ks < 2; ++ks) {                        \
      short8 af[4], bf[4];                                                    \
      _Pragma("unroll") for (int mi = 0; mi < 4; ++mi)                        \
          af[mi] = *(const short8*)&Ar_[swa(wm64 + mi * 16 + col,             \
                                            ks * 32 + qd8)];                  \
      _Pragma("unroll") for (int ni = 0; ni < 4; ++ni)                        \
          bf[ni] = *(const short8*)&Br_[swa(wn64 + ni * 16 + col,             \
                                            ks * 32 + qd8)];                  \
      __builtin_amdgcn_s_setprio(1);                                          \
      _Pragma("unroll") for (int mi = 0; mi < 4; ++mi)                        \
          _Pragma("unroll") for (int ni = 0; ni < 4; ++ni)                    \
          acc[mi][ni] = MFMA_BF16(af[mi], bf[ni], acc[mi][ni], 0, 0, 0);      \
      __builtin_amdgcn_s_setprio(0);                                          \
    }                                                                         \
  } while (0)

  // Prologue: stage tiles 0,1; wait tile 0 (6 newest = tile 1 may fly).
  STAGE(0, 0);
  STAGE(1, 1);
  asm volatile("s_waitcnt vmcnt(6)" ::: "memory");
  __builtin_amdgcn_s_barrier();
  __builtin_amdgcn_sched_barrier(0);

  int cur = 0;
#pragma unroll 1
  for (int kt = 0; kt < 10; ++kt) {
    const int sb = (cur == 0) ? 2 : cur - 1;  // (cur+2)%3
    STAGE(kt + 2, sb);
    COMPUTE(cur);
    // tile kt+1's 6 loads complete; tile kt+2's 6 may remain in flight.
    asm volatile("s_waitcnt vmcnt(6)" ::: "memory");
    __builtin_amdgcn_s_barrier();
    __builtin_amdgcn_sched_barrier(0);
    cur = (cur == 2) ? 0 : cur + 1;
  }
  COMPUTE(cur);  // tile 10
  asm volatile("s_waitcnt vmcnt(0)" ::: "memory");
  __builtin_amdgcn_s_barrier();
  __builtin_amdgcn_sched_barrier(0);
  cur = (cur == 2) ? 0 : cur + 1;
  COMPUTE(cur);  // tile 11

  const int zz = n0p / 768;          // uniform per block
  const int nbase = n0p - zz * 768;  // local n within z

  if (zz < 2) {
    unsigned short* O = (zz == 0) ? O0 : O1;
    const float* bias = (zz == 0) ? b0 : b1;
    const float osc = (zz == 0) ? 0.18033688f : 1.0f;  // log2(e)/sqrt(64) into Q
#pragma unroll
    for (int ni = 0; ni < 4; ++ni) {
      const int n = nbase + wn64 + ni * 16 + col;
      const float bb = bias[n];
#pragma unroll
      for (int mi = 0; mi < 4; ++mi)
#pragma unroll
        for (int r = 0; r < 4; ++r) {
          const int m = m0 + wm64 + mi * 16 + qd * 4 + r;
          O[(size_t)m * 768 + n] = f2b((acc[mi][ni][r] + bb) * osc);
        }
    }
  } else {
    // V^T via LDS transpose: T[nl][ml] 128x256 ushort, chunk XOR-swizzled.
    __syncthreads();  // all waves done with k-loop LDS
    unsigned short* T = LDS;
#pragma unroll
    for (int ni = 0; ni < 4; ++ni) {
      const int nl = wn64 + ni * 16 + col;
      const float bb = b2[nbase + nl];
#pragma unroll
      for (int mi = 0; mi < 4; ++mi) {
        const int ml = wm64 + mi * 16 + qd * 4;
        const int mc = ml >> 3;
        ushort4 o;
        o.x = f2b(acc[mi][ni][0] + bb);
        o.y = f2b(acc[mi][ni][1] + bb);
        o.z = f2b(acc[mi][ni][2] + bb);
        o.w = f2b(acc[mi][ni][3] + bb);
        *(ushort4*)&T[(nl << 8) + (((mc ^ (nl & 31)) & 31) << 3) + (ml & 7)] = o;
      }
    }
    __syncthreads();
    const int nl2 = t >> 2;        // 0..127
    const int seg = t & 3;         // 0..3 (64 m each)
    const int nglob = nbase + nl2; // 0..767
    const int hh = nglob >> 6, dd = nglob & 63;
    const int bb2 = m0 >> 10;
    unsigned short* dstp =
        &OVT[(((size_t)bb2 * 12 + hh) * 64 + dd) * 1024 + (m0 & 1023) + seg * 64];
#pragma unroll
    for (int j = 0; j < 8; ++j) {
      const int mc = seg * 8 + j;
      uint4 vv = *(const uint4*)&T[(nl2 << 8) + (((mc ^ (nl2 & 31)) & 31) << 3)];
      *(uint4*)&dstp[j * 8] = vv;
    }
  }
#undef STAGE
#undef COMPUTE
}

// Flash attention v10 = v7 + TRIPLE-buffered K/V staging with counted vmcnt
// (the qkv-v2 pattern): STAGE(kt+2) at iter top; end-of-iter
// s_waitcnt vmcnt(4) + raw s_barrier leaves kt+2's 4 loads in flight while
// proving kt+1 resident (T4). Gives staging a 2-iter (~1.2K cy) window
// instead of the same-iter vmcnt(0) drain. LDS 48 KB (6 x 8 KB).
// Hazards: WAR fenced by prior iter's barrier; prologue vmcnt(4) also covers
// the 4 Q loads (oldest-first drain); kt=14 drains to 0 (no stage issued).
__global__ __launch_bounds__(256) void attn(
    const unsigned short* __restrict__ Q, const unsigned short* __restrict__ K,
    const unsigned short* __restrict__ VT, float* __restrict__ O) {
  __shared__ __align__(16) unsigned short Ks0[4096];
  __shared__ __align__(16) unsigned short Ks1[4096];
  __shared__ __align__(16) unsigned short Ks2[4096];
  __shared__ __align__(16) unsigned short Vt0[4096];
  __shared__ __align__(16) unsigned short Vt1[4096];
  __shared__ __align__(16) unsigned short Vt2[4096];

  const int g = blockIdx.x;
  const int orig = (g & 7) * 192 + (g >> 3);
  const int qt = orig & 7;
  const int hb = orig >> 3;  // h + 12*b
  const int b = hb / 12;
  const int h = hb - b * 12;

  const int t = threadIdx.x, w = t >> 6, l = t & 63, qd = l >> 4, col = l & 15;
  const size_t bh = (size_t)b * 786432 + (size_t)h * 64;
  const unsigned short* Kb = K + bh;
  const unsigned short* VTb = VT + ((size_t)(b * 12 + h)) * 65536;

  short8 qf[2][2];
  {
    const unsigned short* Qg = Q + bh + (size_t)(qt * 128 + w * 32) * 768;
#pragma unroll
    for (int mi = 0; mi < 2; ++mi)
#pragma unroll
      for (int ks = 0; ks < 2; ++ks)
        qf[mi][ks] =
            *(const short8*)&Qg[(size_t)(mi * 16 + col) * 768 + ks * 32 + qd * 8];
  }

  const int c0 = t, c1 = 256 + t;
  const int r0 = c0 >> 3, cc0 = (c0 ^ r0 ^ (r0 >> 3)) & 7;
  const int r1 = c1 >> 3, cc1 = (c1 ^ r1 ^ (r1 >> 3)) & 7;

#define STAGE_K(ktile, dst)                                             \
  do {                                                                  \
    const unsigned short* Kg_ = Kb + (size_t)(ktile)*49152;             \
    gld16(&Kg_[(size_t)r0 * 768 + cc0 * 8], &dst[c0 * 8]);              \
    gld16(&Kg_[(size_t)r1 * 768 + cc1 * 8], &dst[c1 * 8]);              \
  } while (0)

#define STAGE_V(ktile, dst)                                             \
  do {                                                                  \
    const unsigned short* Vg_ = VTb + (ktile)*64;                       \
    gld16(&Vg_[(size_t)r0 * 1024 + cc0 * 8], &dst[c0 * 8]);             \
    gld16(&Vg_[(size_t)r1 * 1024 + cc1 * 8], &dst[c1 * 8]);             \
  } while (0)

  // Prologue: stage tiles 0 and 1. vmcnt(4) leaves only tile 1's 4 loads
  // outstanding -> tile 0 (and the 4 Q loads, older) proven complete.
  STAGE_K(0, Ks0);
  STAGE_V(0, Vt0);
  STAGE_K(1, Ks1);
  STAGE_V(1, Vt1);

  float4v acc[2][4];
  float4v accl[2];
#pragma unroll
  for (int mi = 0; mi < 2; ++mi) {
    accl[mi] = (float4v)0.0f;
#pragma unroll
    for (int dt = 0; dt < 4; ++dt) acc[mi][dt] = (float4v)0.0f;
  }

  short8 ones;
#pragma unroll
  for (int j = 0; j < 8; ++j) ones[j] = (short)0x3F80;  // bf16 1.0

  asm volatile("s_waitcnt vmcnt(4)" ::: "memory");
  __builtin_amdgcn_s_barrier();
  __builtin_amdgcn_sched_barrier(0);

#define ATTN_ITER(kt, KsR, VtR, KsW, VtW)                                 \
  do {                                                                    \
    if ((kt) + 2 < 16) {                                                  \
      STAGE_K((kt) + 2, KsW);                                             \
      STAGE_V((kt) + 2, VtW);                                             \
    }                                                                     \
    short8 kf[2][4];                                                      \
    _Pragma("unroll") for (int ks = 0; ks < 2; ++ks)                      \
        _Pragma("unroll") for (int ni = 0; ni < 4; ++ni)                  \
        kf[ks][ni] =                                                      \
        *(const short8*)&KsR[swa(ni * 16 + col, ks * 32 + qd * 8)];       \
    float4v sT[2][4];                                                     \
    _Pragma("unroll") for (int mi = 0; mi < 2; ++mi)                      \
        _Pragma("unroll") for (int ni = 0; ni < 4; ++ni)                  \
        sT[mi][ni] = (float4v)0.0f;                                       \
    __builtin_amdgcn_s_setprio(1);                                        \
    _Pragma("unroll") for (int ks = 0; ks < 2; ++ks)                      \
        _Pragma("unroll") for (int ni = 0; ni < 4; ++ni) {                \
      sT[0][ni] = MFMA_BF16(kf[ks][ni], qf[0][ks], sT[0][ni], 0, 0, 0);   \
      sT[1][ni] = MFMA_BF16(kf[ks][ni], qf[1][ks], sT[1][ni], 0, 0, 0);   \
    }                                                                     \
    __builtin_amdgcn_s_setprio(0);                                        \
    _Pragma("unroll") for (int s = 0; s < 2; ++s) {                       \
      short8 pf[2];                                                       \
      _Pragma("unroll") for (int mi = 0; mi < 2; ++mi) {                  \
        float4v sa = sT[mi][s * 2 + 0];                                   \
        float4v sb = sT[mi][s * 2 + 1];                                   \
        unsigned A0 = pk2(__builtin_amdgcn_exp2f(sa[0]),                  \
                          __builtin_amdgcn_exp2f(sa[1]));                 \
        unsigned A1 = pk2(__builtin_amdgcn_exp2f(sa[2]),                  \
                          __builtin_amdgcn_exp2f(sa[3]));                 \
        unsigned B0 = pk2(__builtin_amdgcn_exp2f(sb[0]),                  \
                          __builtin_amdgcn_exp2f(sb[1]));                 \
        unsigned B1 = pk2(__builtin_amdgcn_exp2f(sb[2]),                  \
                          __builtin_amdgcn_exp2f(sb[3]));                 \
        uint2v x0 = __builtin_amdgcn_permlane32_swap(A0, B0, false, false);   \
        uint2v x1 = __builtin_amdgcn_permlane32_swap(A1, B1, false, false);   \
        uint2v y02 = __builtin_amdgcn_permlane16_swap(x0[0], x0[1], false, false); \
        uint2v y13 = __builtin_amdgcn_permlane16_swap(x1[0], x1[1], false, false); \
        union { unsigned u[4]; short8 v; } pu;                            \
        pu.u[0] = y02[0]; pu.u[1] = y13[0];                               \
        pu.u[2] = y02[1]; pu.u[3] = y13[1];                               \
        pf[mi] = pu.v;                                                    \
      }                                                                   \
      const int kk = s * 32 + qd * 8;                                     \
      __builtin_amdgcn_s_setprio(1);                                      \
      _Pragma("unroll") for (int dt = 0; dt < 4; ++dt) {                  \
        short8 vf = *(const short8*)&VtR[swa(dt * 16 + col, kk)];         \
        acc[0][dt] = MFMA_BF16(vf, pf[0], acc[0][dt], 0, 0, 0);           \
        acc[1][dt] = MFMA_BF16(vf, pf[1], acc[1][dt], 0, 0, 0);           \
      }                                                                   \
      accl[0] = MFMA_BF16(ones, pf[0], accl[0], 0, 0, 0);                 \
      accl[1] = MFMA_BF16(ones, pf[1], accl[1], 0, 0, 0);                 \
      __builtin_amdgcn_s_setprio(0);                                      \
    }                                                                     \
    if ((kt) < 14) {                                                      \
      asm volatile("s_waitcnt vmcnt(4)" ::: "memory");                    \
    } else {                                                              \
      asm volatile("s_waitcnt vmcnt(0)" ::: "memory");                    \
    }                                                                     \
    __builtin_amdgcn_s_barrier();                                         \
    __builtin_amdgcn_sched_barrier(0);                                    \
  } while (0)

  // Period-3 buffer rotation: iter kt reads buf kt%3, stages into (kt+2)%3.
#pragma unroll 1
  for (int kt3 = 0; kt3 < 15; kt3 += 3) {
    ATTN_ITER(kt3 + 0, Ks0, Vt0, Ks2, Vt2);
    ATTN_ITER(kt3 + 1, Ks1, Vt1, Ks0, Vt0);
    ATTN_ITER(kt3 + 2, Ks2, Vt2, Ks1, Vt1);
  }
  ATTN_ITER(15, Ks0, Vt0, Ks2, Vt2);  // kt+2=17: no stage; vmcnt(0)+barrier

  float* Og = O + (size_t)(b * 1024 + qt * 128) * 768 + h * 64;
#pragma unroll
  for (int mi = 0; mi < 2; ++mi) {
    const float rl = 1.0f / accl[mi][0];
    const int q = w * 32 + mi * 16 + col;
#pragma unroll
    for (int dt = 0; dt < 4; ++dt) {
      float4 o;
      o.x = acc[mi][dt][0] * rl;
      o.y = acc[mi][dt][1] * rl;
      o.z = acc[mi][dt][2] * rl;
      o.w = acc[mi][dt][3] * rl;
      *(float4*)&Og[(size_t)q * 768 + dt * 16 + qd * 4] = o;
    }
  }
#undef STAGE_K
#undef STAGE_V
#undef ATTN_ITER
}

extern "C" void kernel_launch(void* const* d_in, const int* in_sizes, int n_in,
                              void* d_out, int out_size, void* d_ws, size_t ws_size,
                              hipStream_t stream) {
  const float* hs = (const float*)d_in[0];
  const float* Wq = (const float*)d_in[1];
  const float* bq = (const float*)d_in[2];
  const float* Wk = (const float*)d_in[3];
  const float* bk = (const float*)d_in[4];
  const float* Wv = (const float*)d_in[5];
  const float* bv = (const float*)d_in[6];
  float* out = (float*)d_out;
  char* ws = (char*)d_ws;

  unsigned short* Xb = (unsigned short*)ws;
  unsigned short* Wb = (unsigned short*)(ws + 25165824);
  unsigned short* Qb = (unsigned short*)(ws + 28704768);
  unsigned short* Kb = (unsigned short*)(ws + 53870592);
  unsigned short* Vb = (unsigned short*)(ws + 79036416);  // V^T [b][h][d][s]

  static bool attr_set = false;
  if (!attr_set) {
    hipFuncSetAttribute((const void*)qkv_gemm,
                        hipFuncAttributeMaxDynamicSharedMemorySize, 147456);
    attr_set = true;
  }

  cast_all<<<14016, 256, 0, stream>>>(hs, Wq, Wk, Wv, Xb, Wb);

  qkv_gemm<<<dim3(1152), 512, 147456, stream>>>(Xb, Wb, bq, bk, bv, Qb, Kb, Vb);

  attn<<<dim3(1536), 256, 0, stream>>>(Qb, Kb, Vb, out);
}

// Round 10
// 253.771 us; speedup vs baseline: 1.2637x; 1.0247x over previous
//
#include <hip/hip_runtime.h>
#include <hip/hip_bf16.h>

typedef __attribute__((ext_vector_type(8))) short short8;
typedef __attribute__((ext_vector_type(4))) float float4v;
typedef __attribute__((ext_vector_type(2))) unsigned int uint2v;

#define MFMA_BF16 __builtin_amdgcn_mfma_f32_16x16x32_bf16

__device__ __forceinline__ unsigned short f2b(float f) {
  union { float f; unsigned u; } v; v.f = f;
  unsigned r = v.u + 0x7FFFu + ((v.u >> 16) & 1u);  // round-to-nearest-even
  return (unsigned short)(r >> 16);
}

__device__ __forceinline__ unsigned pk2(float x, float y) {
  float2 v; v.x = x; v.y = y;
  __hip_bfloat162 h = __float22bfloat162_rn(v);
  union { __hip_bfloat162 h; unsigned u; } c; c.h = h;
  return c.u;
}

// async global->LDS, 16B per lane. LDS dest must be wave-uniform + lane*16.
__device__ __forceinline__ void gld16(const unsigned short* g, unsigned short* l) {
  __builtin_amdgcn_global_load_lds(
      (const __attribute__((address_space(1))) unsigned int*)g,
      (__attribute__((address_space(3))) unsigned int*)l, 16, 0, 0);
}

// Swizzled element index within a [rows][64] bf16 LDS tile.
__device__ __forceinline__ int swa(int r, int k) {
  return (r << 6) + ((((k >> 3) ^ r ^ (r >> 3)) & 7) << 3) + (k & 7);
}

// Fused cast: hs (12288 blocks) + Wq/Wk/Wv (576 blocks each) in one launch.
// (r8 lesson: do NOT fuse this into the GEMM — the GEMM re-reads its operands
// ~3x; casting once keeps those re-reads bf16.)
__global__ __launch_bounds__(256) void cast_all(
    const float* __restrict__ hs, const float* __restrict__ Wq,
    const float* __restrict__ Wk, const float* __restrict__ Wv,
    unsigned short* __restrict__ Xb, unsigned short* __restrict__ Wb) {
  const int blk = blockIdx.x;
  const float* src;
  unsigned short* dst;
  int i;
  if (blk < 12288) {
    i = blk * 256 + threadIdx.x;
    src = hs;
    dst = Xb;
  } else {
    const int x = blk - 12288;       // 0..1727
    const int z = x / 576;           // 0,1,2
    i = (x - z * 576) * 256 + threadIdx.x;
    src = (z == 0) ? Wq : (z == 1 ? Wk : Wv);
    dst = Wb + (size_t)z * 589824;
  }
  float4 f = ((const float4*)src)[i];
  uint2 o;
  o.x = pk2(f.x, f.y);
  o.y = pk2(f.z, f.w);
  ((uint2*)dst)[i] = o;
}

// QKV GEMM v2 (verified 87 us): BM=256 BN=128 BK=64, 8 waves (4M x 2N),
// per-wave 64x64 out. TRIPLE-buffered LDS (144 KB dynamic, 1 block/CU),
// prefetch depth 2: STAGE(t+2) at tile-t top, per-tile counted s_waitcnt
// vmcnt(6). Raw s_barrier once per tile. Grid 1152, XCD-swizzled.
// z=0 out pre-scaled by log2(e)/sqrt(64); z=2 transposed to [b][h][d][s].
__global__ __launch_bounds__(512) void qkv_gemm(
    const unsigned short* __restrict__ X, const unsigned short* __restrict__ Wall,
    const float* __restrict__ b0, const float* __restrict__ b1, const float* __restrict__ b2,
    unsigned short* __restrict__ O0, unsigned short* __restrict__ O1, unsigned short* __restrict__ OVT) {
  extern __shared__ __align__(16) unsigned short LDS[];  // 3 * (16384 A + 8192 B)

  const int g = blockIdx.x;
  const int orig = (g & 7) * 144 + (g >> 3);
  const int mblk = orig / 18;
  const int nblk = orig - mblk * 18;
  const int m0 = mblk * 256, n0p = nblk * 128;

  const int t = threadIdx.x, w = t >> 6, l = t & 63, qd = l >> 4, col = l & 15;
  const int wm64 = (w & 3) * 64, wn64 = (w >> 2) * 64;
  const int qd8 = qd * 8;

  const int cA0 = t, cA1 = 512 + t, cA2 = 1024 + t, cA3 = 1536 + t;
  const int rA0 = cA0 >> 3, rA1 = cA1 >> 3, rA2 = cA2 >> 3, rA3 = cA3 >> 3;
  const int pA0 = (cA0 ^ rA0 ^ (rA0 >> 3)) & 7, pA1 = (cA1 ^ rA1 ^ (rA1 >> 3)) & 7;
  const int pA2 = (cA2 ^ rA2 ^ (rA2 >> 3)) & 7, pA3 = (cA3 ^ rA3 ^ (rA3 >> 3)) & 7;
  const int cB0 = t, cB1 = 512 + t;
  const int rB0 = cB0 >> 3, rB1 = cB1 >> 3;
  const int pB0 = (cB0 ^ rB0 ^ (rB0 >> 3)) & 7, pB1 = (cB1 ^ rB1 ^ (rB1 >> 3)) & 7;

  const unsigned short* Xa0 = X + (size_t)(m0 + rA0) * 768 + pA0 * 8;
  const unsigned short* Xa1 = X + (size_t)(m0 + rA1) * 768 + pA1 * 8;
  const unsigned short* Xa2 = X + (size_t)(m0 + rA2) * 768 + pA2 * 8;
  const unsigned short* Xa3 = X + (size_t)(m0 + rA3) * 768 + pA3 * 8;
  const unsigned short* Wb0 = Wall + (size_t)(n0p + rB0) * 768 + pB0 * 8;
  const unsigned short* Wb1 = Wall + (size_t)(n0p + rB1) * 768 + pB1 * 8;
  const int dA0 = cA0 * 8, dA1 = cA1 * 8, dA2 = cA2 * 8, dA3 = cA3 * 8;
  const int dB0 = cB0 * 8, dB1 = cB1 * 8;

#define STAGE(kt, sb)                                         \
  do {                                                        \
    unsigned short* SA_ = LDS + (sb)*24576;                   \
    unsigned short* SB_ = SA_ + 16384;                        \
    const int kk_ = (kt)*64;                                  \
    gld16(Xa0 + kk_, SA_ + dA0);                              \
    gld16(Xa1 + kk_, SA_ + dA1);                              \
    gld16(Xa2 + kk_, SA_ + dA2);                              \
    gld16(Xa3 + kk_, SA_ + dA3);                              \
    gld16(Wb0 + kk_, SB_ + dB0);                              \
    gld16(Wb1 + kk_, SB_ + dB1);                              \
  } while (0)

  float4v acc[4][4];
#pragma unroll
  for (int i = 0; i < 4; ++i)
#pragma unroll
    for (int j = 0; j < 4; ++j) acc[i][j] = (float4v)0.0f;

#define COMPUTE(cur)                                                          \
  do {                                                                        \
    const unsigned short* Ar_ = LDS + (cur)*24576;                            \
    const unsigned short* Br_ = Ar_ + 16384;                                  \
    _Pragma("unroll") for (int ks = 0; ks < 2; ++ks) {                        \
      short8 af[4], bf[4];                                                    \
      _Pragma("unroll") for (int mi = 0; mi < 4; ++mi)                        \
          af[mi] = *(const short8*)&Ar_[swa(wm64 + mi * 16 + col,             \
                                            ks * 32 + qd8)];                  \
      _Pragma("unroll") for (int ni = 0; ni < 4; ++ni)                        \
          bf[ni] = *(const short8*)&Br_[swa(wn64 + ni * 16 + col,             \
                                            ks * 32 + qd8)];                  \
      __builtin_amdgcn_s_setprio(1);                                          \
      _Pragma("unroll") for (int mi = 0; mi < 4; ++mi)                        \
          _Pragma("unroll") for (int ni = 0; ni < 4; ++ni)                    \
          acc[mi][ni] = MFMA_BF16(af[mi], bf[ni], acc[mi][ni], 0, 0, 0);      \
      __builtin_amdgcn_s_setprio(0);                                          \
    }                                                                         \
  } while (0)

  STAGE(0, 0);
  STAGE(1, 1);
  asm volatile("s_waitcnt vmcnt(6)" ::: "memory");
  __builtin_amdgcn_s_barrier();
  __builtin_amdgcn_sched_barrier(0);

  int cur = 0;
#pragma unroll 1
  for (int kt = 0; kt < 10; ++kt) {
    const int sb = (cur == 0) ? 2 : cur - 1;  // (cur+2)%3
    STAGE(kt + 2, sb);
    COMPUTE(cur);
    asm volatile("s_waitcnt vmcnt(6)" ::: "memory");
    __builtin_amdgcn_s_barrier();
    __builtin_amdgcn_sched_barrier(0);
    cur = (cur == 2) ? 0 : cur + 1;
  }
  COMPUTE(cur);  // tile 10
  asm volatile("s_waitcnt vmcnt(0)" ::: "memory");
  __builtin_amdgcn_s_barrier();
  __builtin_amdgcn_sched_barrier(0);
  cur = (cur == 2) ? 0 : cur + 1;
  COMPUTE(cur);  // tile 11

  const int zz = n0p / 768;
  const int nbase = n0p - zz * 768;

  if (zz < 2) {
    unsigned short* O = (zz == 0) ? O0 : O1;
    const float* bias = (zz == 0) ? b0 : b1;
    const float osc = (zz == 0) ? 0.18033688f : 1.0f;  // log2(e)/sqrt(64) into Q
#pragma unroll
    for (int ni = 0; ni < 4; ++ni) {
      const int n = nbase + wn64 + ni * 16 + col;
      const float bb = bias[n];
#pragma unroll
      for (int mi = 0; mi < 4; ++mi)
#pragma unroll
        for (int r = 0; r < 4; ++r) {
          const int m = m0 + wm64 + mi * 16 + qd * 4 + r;
          O[(size_t)m * 768 + n] = f2b((acc[mi][ni][r] + bb) * osc);
        }
    }
  } else {
    __syncthreads();
    unsigned short* T = LDS;
#pragma unroll
    for (int ni = 0; ni < 4; ++ni) {
      const int nl = wn64 + ni * 16 + col;
      const float bb = b2[nbase + nl];
#pragma unroll
      for (int mi = 0; mi < 4; ++mi) {
        const int ml = wm64 + mi * 16 + qd * 4;
        const int mc = ml >> 3;
        ushort4 o;
        o.x = f2b(acc[mi][ni][0] + bb);
        o.y = f2b(acc[mi][ni][1] + bb);
        o.z = f2b(acc[mi][ni][2] + bb);
        o.w = f2b(acc[mi][ni][3] + bb);
        *(ushort4*)&T[(nl << 8) + (((mc ^ (nl & 31)) & 31) << 3) + (ml & 7)] = o;
      }
    }
    __syncthreads();
    const int nl2 = t >> 2;
    const int seg = t & 3;
    const int nglob = nbase + nl2;
    const int hh = nglob >> 6, dd = nglob & 63;
    const int bb2 = m0 >> 10;
    unsigned short* dstp =
        &OVT[(((size_t)bb2 * 12 + hh) * 64 + dd) * 1024 + (m0 & 1023) + seg * 64];
#pragma unroll
    for (int j = 0; j < 8; ++j) {
      const int mc = seg * 8 + j;
      uint4 vv = *(const uint4*)&T[(nl2 << 8) + (((mc ^ (nl2 & 31)) & 31) << 3)];
      *(uint4*)&dstp[j * 8] = vv;
    }
  }
#undef STAGE
#undef COMPUTE
}

// Flash attention v11: T15-style 2-deep score pipeline. QK(kt) computes into
// one score block while softmax+PV of tile kt-1 (independent registers) runs
// — the scheduler fills MFMA shadows with the previous tile's exp2/pack VALU
// and vice versa, breaking the QK->SM->PV serial chain that r9 showed was
// binding (staging-depth experiment was null; no pipe saturated).
// Staging: K triple-buffer (stage K[kt+2] at iter kt), V triple-buffer
// (stage V[kt+1] at iter kt; V must outlive one extra iter vs K since PV
// consumes it one iteration late). End-of-iter s_waitcnt vmcnt(4) proves
// K[kt+1], V[kt] resident while this iter's 4 loads stay in flight.
// First-ks MFMA uses a shared zero C operand (no 32 per-iter reg zeroing).
// sA/sB named score blocks, fully unrolled loop (no runtime indexing).
__global__ __launch_bounds__(256) void attn(
    const unsigned short* __restrict__ Q, const unsigned short* __restrict__ K,
    const unsigned short* __restrict__ VT, float* __restrict__ O) {
  __shared__ __align__(16) unsigned short Ks0[4096];
  __shared__ __align__(16) unsigned short Ks1[4096];
  __shared__ __align__(16) unsigned short Ks2[4096];
  __shared__ __align__(16) unsigned short Vt0[4096];
  __shared__ __align__(16) unsigned short Vt1[4096];
  __shared__ __align__(16) unsigned short Vt2[4096];

  const int g = blockIdx.x;
  const int orig = (g & 7) * 192 + (g >> 3);
  const int qt = orig & 7;
  const int hb = orig >> 3;  // h + 12*b
  const int b = hb / 12;
  const int h = hb - b * 12;

  const int t = threadIdx.x, w = t >> 6, l = t & 63, qd = l >> 4, col = l & 15;
  const size_t bh = (size_t)b * 786432 + (size_t)h * 64;
  const unsigned short* Kb = K + bh;
  const unsigned short* VTb = VT + ((size_t)(b * 12 + h)) * 65536;

  short8 qf[2][2];
  {
    const unsigned short* Qg = Q + bh + (size_t)(qt * 128 + w * 32) * 768;
#pragma unroll
    for (int mi = 0; mi < 2; ++mi)
#pragma unroll
      for (int ks = 0; ks < 2; ++ks)
        qf[mi][ks] =
            *(const short8*)&Qg[(size_t)(mi * 16 + col) * 768 + ks * 32 + qd * 8];
  }

  const int c0 = t, c1 = 256 + t;
  const int r0 = c0 >> 3, cc0 = (c0 ^ r0 ^ (r0 >> 3)) & 7;
  const int r1 = c1 >> 3, cc1 = (c1 ^ r1 ^ (r1 >> 3)) & 7;

#define STAGE_K(ktile, dst)                                             \
  do {                                                                  \
    const unsigned short* Kg_ = Kb + (size_t)(ktile)*49152;             \
    gld16(&Kg_[(size_t)r0 * 768 + cc0 * 8], &dst[c0 * 8]);              \
    gld16(&Kg_[(size_t)r1 * 768 + cc1 * 8], &dst[c1 * 8]);              \
  } while (0)

#define STAGE_V(ktile, dst)                                             \
  do {                                                                  \
    const unsigned short* Vg_ = VTb + (ktile)*64;                       \
    gld16(&Vg_[(size_t)r0 * 1024 + cc0 * 8], &dst[c0 * 8]);             \
    gld16(&Vg_[(size_t)r1 * 1024 + cc1 * 8], &dst[c1 * 8]);             \
  } while (0)

  float4v acc[2][4];
  float4v accl[2];
#pragma unroll
  for (int mi = 0; mi < 2; ++mi) {
    accl[mi] = (float4v)0.0f;
#pragma unroll
    for (int dt = 0; dt < 4; ++dt) acc[mi][dt] = (float4v)0.0f;
  }
  float4v sA[2][4], sB[2][4];
  const float4v Zv = (float4v)0.0f;

  short8 ones;
#pragma unroll
  for (int j = 0; j < 8; ++j) ones[j] = (short)0x3F80;  // bf16 1.0

  // QK of one K-tile into score block S (first ks uses shared zero C).
#define QK_TILE(KsR, S)                                                   \
  do {                                                                    \
    short8 kf[2][4];                                                      \
    _Pragma("unroll") for (int ks = 0; ks < 2; ++ks)                      \
        _Pragma("unroll") for (int ni = 0; ni < 4; ++ni)                  \
        kf[ks][ni] =                                                      \
        *(const short8*)&KsR[swa(ni * 16 + col, ks * 32 + qd * 8)];       \
    __builtin_amdgcn_s_setprio(1);                                        \
    _Pragma("unroll") for (int ni = 0; ni < 4; ++ni) {                    \
      S[0][ni] = MFMA_BF16(kf[0][ni], qf[0][0], Zv, 0, 0, 0);             \
      S[1][ni] = MFMA_BF16(kf[0][ni], qf[1][0], Zv, 0, 0, 0);             \
    }                                                                     \
    _Pragma("unroll") for (int ni = 0; ni < 4; ++ni) {                    \
      S[0][ni] = MFMA_BF16(kf[1][ni], qf[0][1], S[0][ni], 0, 0, 0);       \
      S[1][ni] = MFMA_BF16(kf[1][ni], qf[1][1], S[1][ni], 0, 0, 0);       \
    }                                                                     \
    __builtin_amdgcn_s_setprio(0);                                        \
  } while (0)

  // Softmax + PV of a previously-computed score block S against V tile VtR.
#define SMPV(S, VtR)                                                      \
  do {                                                                    \
    _Pragma("unroll") for (int s = 0; s < 2; ++s) {                       \
      short8 pf[2];                                                       \
      _Pragma("unroll") for (int mi = 0; mi < 2; ++mi) {                  \
        float4v sa = S[mi][s * 2 + 0];                                    \
        float4v sb = S[mi][s * 2 + 1];                                    \
        unsigned A0 = pk2(__builtin_amdgcn_exp2f(sa[0]),                  \
                          __builtin_amdgcn_exp2f(sa[1]));                 \
        unsigned A1 = pk2(__builtin_amdgcn_exp2f(sa[2]),                  \
                          __builtin_amdgcn_exp2f(sa[3]));                 \
        unsigned B0 = pk2(__builtin_amdgcn_exp2f(sb[0]),                  \
                          __builtin_amdgcn_exp2f(sb[1]));                 \
        unsigned B1 = pk2(__builtin_amdgcn_exp2f(sb[2]),                  \
                          __builtin_amdgcn_exp2f(sb[3]));                 \
        uint2v x0 = __builtin_amdgcn_permlane32_swap(A0, B0, false, false);   \
        uint2v x1 = __builtin_amdgcn_permlane32_swap(A1, B1, false, false);   \
        uint2v y02 = __builtin_amdgcn_permlane16_swap(x0[0], x0[1], false, false); \
        uint2v y13 = __builtin_amdgcn_permlane16_swap(x1[0], x1[1], false, false); \
        union { unsigned u[4]; short8 v; } pu;                            \
        pu.u[0] = y02[0]; pu.u[1] = y13[0];                               \
        pu.u[2] = y02[1]; pu.u[3] = y13[1];                               \
        pf[mi] = pu.v;                                                    \
      }                                                                   \
      const int kk = s * 32 + qd * 8;                                     \
      __builtin_amdgcn_s_setprio(1);                                      \
      _Pragma("unroll") for (int dt = 0; dt < 4; ++dt) {                  \
        short8 vf = *(const short8*)&VtR[swa(dt * 16 + col, kk)];         \
        acc[0][dt] = MFMA_BF16(vf, pf[0], acc[0][dt], 0, 0, 0);           \
        acc[1][dt] = MFMA_BF16(vf, pf[1], acc[1][dt], 0, 0, 0);           \
      }                                                                   \
      accl[0] = MFMA_BF16(ones, pf[0], accl[0], 0, 0, 0);                 \
      accl[1] = MFMA_BF16(ones, pf[1], accl[1], 0, 0, 0);                 \
      __builtin_amdgcn_s_setprio(0);                                      \
    }                                                                     \
  } while (0)

#define W4 asm volatile("s_waitcnt vmcnt(4)" ::: "memory")
#define W2 asm volatile("s_waitcnt vmcnt(2)" ::: "memory")
#define W0 asm volatile("s_waitcnt vmcnt(0)" ::: "memory")
#define BAR                                                               \
  do {                                                                    \
    __builtin_amdgcn_s_barrier();                                         \
    __builtin_amdgcn_sched_barrier(0);                                    \
  } while (0)

  // Pipelined iteration kt (1..14): stage K[kt+2], V[kt+1]; QK(kt)->Snew;
  // SMPV(Sold = tile kt-1) against V[kt-1]; counted wait; barrier.
#define PIPE(kt, KR, VR, KW, VW, Snew, Sold, WAIT)                        \
  do {                                                                    \
    if ((kt) + 2 < 16) STAGE_K((kt) + 2, KW);                             \
    if ((kt) + 1 < 16) STAGE_V((kt) + 1, VW);                             \
    QK_TILE(KR, Snew);                                                    \
    SMPV(Sold, VR);                                                       \
    WAIT;                                                                 \
    BAR;                                                                  \
  } while (0)

  // Prologue: K0,V0,K1,V1,K2 staged; drain; barrier; QK(0); barrier
  // (second barrier protects Ks0 from iter-1's K3 stage overwriting it
  // while another wave still reads K0).
  STAGE_K(0, Ks0);
  STAGE_V(0, Vt0);
  STAGE_K(1, Ks1);
  STAGE_V(1, Vt1);
  STAGE_K(2, Ks2);
  W0;
  BAR;
  QK_TILE(Ks0, sA);
  BAR;

  // Buffer map: K tile kt in Ks[kt%3]; V tile kt in Vt[kt%3].
  PIPE(1,  Ks1, Vt0, Ks0, Vt2, sB, sA, W4);
  PIPE(2,  Ks2, Vt1, Ks1, Vt0, sA, sB, W4);
  PIPE(3,  Ks0, Vt2, Ks2, Vt1, sB, sA, W4);
  PIPE(4,  Ks1, Vt0, Ks0, Vt2, sA, sB, W4);
  PIPE(5,  Ks2, Vt1, Ks1, Vt0, sB, sA, W4);
  PIPE(6,  Ks0, Vt2, Ks2, Vt1, sA, sB, W4);
  PIPE(7,  Ks1, Vt0, Ks0, Vt2, sB, sA, W4);
  PIPE(8,  Ks2, Vt1, Ks1, Vt0, sA, sB, W4);
  PIPE(9,  Ks0, Vt2, Ks2, Vt1, sB, sA, W4);
  PIPE(10, Ks1, Vt0, Ks0, Vt2, sA, sB, W4);
  PIPE(11, Ks2, Vt1, Ks1, Vt0, sB, sA, W4);
  PIPE(12, Ks0, Vt2, Ks2, Vt1, sA, sB, W4);
  PIPE(13, Ks1, Vt0, Ks0, Vt2, sB, sA, W4);
  PIPE(14, Ks2, Vt1, Ks0, Vt0, sA, sB, W0);  // stages only V15 (K guard)
  // kt=15: no stages, no further barrier needed.
  QK_TILE(Ks0, sB);   // K15 (staged at kt=13, proven by kt=14's W0)
  SMPV(sA, Vt2);      // tile 14
  SMPV(sB, Vt0);      // tile 15 (V15 staged at kt=14, proven by W0)

  float* Og = O + (size_t)(b * 1024 + qt * 128) * 768 + h * 64;
#pragma unroll
  for (int mi = 0; mi < 2; ++mi) {
    const float rl = 1.0f / accl[mi][0];
    const int q = w * 32 + mi * 16 + col;
#pragma unroll
    for (int dt = 0; dt < 4; ++dt) {
      float4 o;
      o.x = acc[mi][dt][0] * rl;
      o.y = acc[mi][dt][1] * rl;
      o.z = acc[mi][dt][2] * rl;
      o.w = acc[mi][dt][3] * rl;
      *(float4*)&Og[(size_t)q * 768 + dt * 16 + qd * 4] = o;
    }
  }
#undef STAGE_K
#undef STAGE_V
#undef QK_TILE
#undef SMPV
#undef PIPE
#undef W4
#undef W2
#undef W0
#undef BAR
}

extern "C" void kernel_launch(void* const* d_in, const int* in_sizes, int n_in,
                              void* d_out, int out_size, void* d_ws, size_t ws_size,
                              hipStream_t stream) {
  const float* hs = (const float*)d_in[0];
  const float* Wq = (const float*)d_in[1];
  const float* bq = (const float*)d_in[2];
  const float* Wk = (const float*)d_in[3];
  const float* bk = (const float*)d_in[4];
  const float* Wv = (const float*)d_in[5];
  const float* bv = (const float*)d_in[6];
  float* out = (float*)d_out;
  char* ws = (char*)d_ws;

  unsigned short* Xb = (unsigned short*)ws;
  unsigned short* Wb = (unsigned short*)(ws + 25165824);
  unsigned short* Qb = (unsigned short*)(ws + 28704768);
  unsigned short* Kb = (unsigned short*)(ws + 53870592);
  unsigned short* Vb = (unsigned short*)(ws + 79036416);  // V^T [b][h][d][s]

  static bool attr_set = false;
  if (!attr_set) {
    hipFuncSetAttribute((const void*)qkv_gemm,
                        hipFuncAttributeMaxDynamicSharedMemorySize, 147456);
    attr_set = true;
  }

  cast_all<<<14016, 256, 0, stream>>>(hs, Wq, Wk, Wv, Xb, Wb);

  qkv_gemm<<<dim3(1152), 512, 147456, stream>>>(Xb, Wb, bq, bk, bv, Qb, Kb, Vb);

  attn<<<dim3(1536), 256, 0, stream>>>(Qb, Kb, Vb, out);
}